// Round 9
// baseline (557.074 us; speedup 1.0000x reference)
//
#include <hip/hip_runtime.h>
#include <hip/hip_bf16.h>
#include <math.h>

// Problem dims (fixed by reference)
#define BB 32
#define LL 12
#define NN 4096
#define CIN 4
#define HID 64
#define GRID_F 8
#define NSTEP 10
#define DTS 0.1f
#define BLN (BB*LL)          // 384 rows (b*L+l)
#define ELEMS (BB*LL*NN)     // 1572864
#define K4 4096

#define L2E 1.4426950408889634f
#define LN2 0.6931471805599453f

typedef __attribute__((ext_vector_type(8))) short short8;
typedef __attribute__((ext_vector_type(16))) float f32x16;
typedef __attribute__((ext_vector_type(2))) float f32x2;

union FragU { unsigned u[4]; uint4 v; short8 s; };
union BF2U { __hip_bfloat162 h; unsigned u; };

__device__ __forceinline__ unsigned pack2bf(float a, float b) {
    // a -> high 16 bits, b -> low 16 bits (both RNE-rounded bf16)
    unsigned ua = __float_as_uint(a);
    unsigned ub = __float_as_uint(b);
    ua += 0x7FFFu + ((ua >> 16) & 1u);
    ub += 0x7FFFu + ((ub >> 16) & 1u);
    return (ua & 0xFFFF0000u) | (ub >> 16);
}

__device__ __forceinline__ unsigned short bf16of(float a) {
    unsigned ua = __float_as_uint(a);
    ua += 0x7FFFu + ((ua >> 16) & 1u);
    return (unsigned short)(ua >> 16);
}

__device__ __forceinline__ f32x16 fzero16() {
    f32x16 z;
#pragma unroll
    for (int i = 0; i < 16; ++i) z[i] = 0.f;
    return z;
}

// ---------------------------------------------------------------------------
// Kernel 1: base_pred[b,l,n] = prior + tanh(adapter)*kasa_gate  (f32 + bf16)
// ---------------------------------------------------------------------------
__global__ __launch_bounds__(256) void base_pred_kernel(
    const float* __restrict__ hd,   // [B][L][N][4]
    const float* __restrict__ Wk,   // [12][12]
    const float* __restrict__ bk,   // [12]
    const float* __restrict__ Wad,  // [12][12]
    const float* __restrict__ bad,  // [12]
    const float* __restrict__ kgp,  // scalar
    float* __restrict__ base,       // [384][4096]
    unsigned short* __restrict__ base16)  // nullable [384][4096] bf16
{
    int idx = blockIdx.x * 256 + threadIdx.x;     // 0 .. 131071  (b,n)
    int b = idx >> 12;
    int n = idx & 4095;
    const float* hb = hd + (size_t)b * (LL * NN * CIN) + (size_t)n * CIN;

    float h0[12];
    float prior = 0.f;
#pragma unroll
    for (int t = 0; t < 12; ++t) {
        float4 v = *reinterpret_cast<const float4*>(hb + (size_t)t * (NN * CIN));
        h0[t] = v.x;
        if (t == 11) prior = v.w;
    }
    float kgate = kgp[0];

    float kr[12];
#pragma unroll
    for (int l = 0; l < 12; ++l) {
        float p = bk[l];
#pragma unroll
        for (int t = 0; t < 12; ++t) p = fmaf(h0[t], Wk[l * 12 + t], p);
        kr[l] = p;
    }
#pragma unroll
    for (int o = 0; o < 12; ++o) {
        float p = bad[o];
#pragma unroll
        for (int l = 0; l < 12; ++l) p = fmaf(kr[l], Wad[o * 12 + l], p);
        float val = prior + tanhf(p) * kgate;
        size_t off = ((size_t)(b * 12 + o)) * NN + n;
        base[off] = val;
        if (base16) base16[off] = bf16of(val);
    }
}

// ---------------------------------------------------------------------------
// Kernel 2: combined C-init table (f32):
//   tcomb[k][tile][hi][r] = L2E * ( b1[h] + sum_g cos((g+1)t_k)*A1[h][2][g]
//                                          + sin((g+1)t_k)*B1[h][2][g] )
//   h = tile*32 + (r&3) + 8*(r>>2) + 4*hi   (the MFMA C/D row map)
// ---------------------------------------------------------------------------
__global__ void tcomb_kernel(const float* __restrict__ A1,
                             const float* __restrict__ B1,
                             const float* __restrict__ b1,
                             float* __restrict__ tcomb)   // [10*64]
{
    int idx = blockIdx.x * blockDim.x + threadIdx.x;
    if (idx >= NSTEP * 64) return;
    int k    = idx >> 6;
    int rem  = idx & 63;
    int tile = rem >> 5;
    int hi   = (rem >> 4) & 1;
    int r    = rem & 15;
    int h = tile * 32 + (r & 3) + 8 * (r >> 2) + 4 * hi;
    float t = DTS * (float)k;
    float val = b1[h];
#pragma unroll
    for (int g = 0; g < GRID_F; ++g) {
        float ang = t * (float)(g + 1);
        val += cosf(ang) * A1[(h * 3 + 2) * 8 + g] + sinf(ang) * B1[(h * 3 + 2) * 8 + g];
    }
    tcomb[idx] = val * L2E;
}

// ---------------------------------------------------------------------------
// Kernel 2b: U f32 [n][m] -> U16 bf16 [n][m]  and  UT16 bf16 [m][n]
// ---------------------------------------------------------------------------
__global__ __launch_bounds__(256) void u_convert_kernel(
    const float* __restrict__ U,
    unsigned short* __restrict__ U16,
    unsigned short* __restrict__ UT16)
{
    __shared__ unsigned short tile[64][66];
    const int t = threadIdx.x;
    const int bx = blockIdx.x;   // col tile (m)
    const int by = blockIdx.y;   // row tile (n)
    {
        int r  = t >> 2;           // 0..63
        int c0 = (t & 3) * 16;
        size_t gr = (size_t)(by * 64 + r);
        size_t gc = (size_t)(bx * 64) + c0;
        const float4* src = reinterpret_cast<const float4*>(U + gr * K4 + gc);
        unsigned ou[8];
#pragma unroll
        for (int i = 0; i < 4; ++i) {
            float4 v = src[i];
            ou[2 * i]     = pack2bf(v.y, v.x);
            ou[2 * i + 1] = pack2bf(v.w, v.z);
        }
        uint4* dst = reinterpret_cast<uint4*>(&U16[gr * K4 + gc]);
        dst[0] = make_uint4(ou[0], ou[1], ou[2], ou[3]);
        dst[1] = make_uint4(ou[4], ou[5], ou[6], ou[7]);
#pragma unroll
        for (int i = 0; i < 8; ++i) {
            tile[r][c0 + 2 * i]     = (unsigned short)(ou[i] & 0xFFFFu);
            tile[r][c0 + 2 * i + 1] = (unsigned short)(ou[i] >> 16);
        }
    }
    __syncthreads();
    {
        int c  = t >> 2;           // local col
        int r0 = (t & 3) * 16;
        unsigned ou[8];
#pragma unroll
        for (int i = 0; i < 8; ++i) {
            unsigned lo = tile[r0 + 2 * i][c];
            unsigned hi = tile[r0 + 2 * i + 1][c];
            ou[i] = lo | (hi << 16);
        }
        size_t gm = (size_t)(bx * 64 + c);
        size_t gn = (size_t)(by * 64) + r0;
        uint4* dst = reinterpret_cast<uint4*>(&UT16[gm * K4 + gn]);
        dst[0] = make_uint4(ou[0], ou[1], ou[2], ou[3]);
        dst[1] = make_uint4(ou[4], ou[5], ou[6], ou[7]);
    }
}

// ---------------------------------------------------------------------------
// MFMA GEMM (64x64 tile, 384 blocks -> fills the 256-CU chip):
//   D[M'][N'] = alpha * A·Bt^T   (both operands k-contiguous bf16)
//   TRANS_STORE=false: C[d_m][d_n] = alpha*D        (GEMM1: C=xc f32)
//   TRANS_STORE=true : C[d_n][d_m] = C0 + alpha*D   (GEMM2: C=out, C0=base)
// 4 waves (2x2) of 32x32, BK=64, double-buffered swizzled LDS.
// ---------------------------------------------------------------------------
template <bool TRANS_STORE>
__global__ __launch_bounds__(256) void gemm_mfma64(
    const unsigned short* __restrict__ A,
    const unsigned short* __restrict__ Bt,
    const float* __restrict__ C0,
    float* __restrict__ C,
    const float* __restrict__ alpha_ptr,
    float alpha_const)
{
    __shared__ uint4 lds4[2][1024];   // [buf][A 8KB | B 8KB]
    unsigned char* ldsc = reinterpret_cast<unsigned char*>(&lds4[0][0]);

    const int tid  = threadIdx.x;
    const int lane = tid & 63;
    const int l31  = lane & 31;
    const int hi   = lane >> 5;
    const int w    = tid >> 6;
    const int wr   = w >> 1;
    const int wc   = w & 1;
    const int m0   = blockIdx.y * 64;
    const int n0   = blockIdx.x * 64;

    // staging: 128 rows (A 0..63 | B 64..127), 2 threads/row, 64B each
    const int srow = tid >> 1;
    const int skb  = (tid & 1) * 64;
    const bool isB = srow >= 64;
    const int  rloc = srow & 63;
    const unsigned char* gsrc = (isB ? (const unsigned char*)Bt + ((size_t)(n0 + rloc) * K4) * 2
                                     : (const unsigned char*)A  + ((size_t)(m0 + rloc) * K4) * 2) + skb;
    const int swbase = (isB ? 8192 : 0) + rloc * 128;
    const int sswz   = (rloc & 7) << 4;

    uint4 rg[4];
    auto LOADG = [&](int kt) {
        const size_t kby = (size_t)kt * 128;
#pragma unroll
        for (int i = 0; i < 4; ++i)
            rg[i] = *reinterpret_cast<const uint4*>(gsrc + kby + i * 16);
    };
    auto WRITE_LDS = [&](int buf) {
        unsigned char* p = ldsc + buf * 16384;
#pragma unroll
        for (int i = 0; i < 4; ++i)
            *reinterpret_cast<uint4*>(p + (swbase + ((skb + i * 16) ^ sswz))) = rg[i];
    };

    f32x16 acc = fzero16();

    const int raw = wr * 32 + l31;
    const int rbw = wc * 32 + l31;
    const int khb = hi * 16;
    const int aswz = (raw & 7) << 4;
    const int bswz = (rbw & 7) << 4;

    LOADG(0);
    WRITE_LDS(0);

    for (int kt = 0; kt < K4 / 64; ++kt) {
        __syncthreads();
        if (kt + 1 < K4 / 64) LOADG(kt + 1);
        const unsigned char* p = ldsc + (kt & 1) * 16384;
#pragma unroll
        for (int ks = 0; ks < 4; ++ks) {
            const int kc = ks * 32 + khb;
            short8 a = *reinterpret_cast<const short8*>(p + (raw * 128 + (kc ^ aswz)));
            short8 b = *reinterpret_cast<const short8*>(p + 8192 + (rbw * 128 + (kc ^ bswz)));
            acc = __builtin_amdgcn_mfma_f32_32x32x16_bf16(a, b, acc, 0, 0, 0);
        }
        if (kt + 1 < K4 / 64) WRITE_LDS((kt + 1) & 1);
    }

    float alpha = alpha_const;
    if (alpha_ptr) alpha *= alpha_ptr[0];

    if (!TRANS_STORE) {
        int colg = n0 + wc * 32 + l31;
        int rowb = m0 + wr * 32 + 4 * hi;
#pragma unroll
        for (int r = 0; r < 16; ++r) {
            int row = rowb + (r & 3) + 8 * (r >> 2);
            C[(size_t)row * K4 + colg] = acc[r] * alpha;
        }
    } else {
        int rowo = n0 + wc * 32 + l31;
        int mb   = m0 + wr * 32 + 4 * hi;
#pragma unroll
        for (int q = 0; q < 4; ++q) {
            size_t off = (size_t)rowo * K4 + mb + 8 * q;
            float4 c0v = *reinterpret_cast<const float4*>(&C0[off]);
            float4 v;
            v.x = fmaf(acc[4 * q + 0], alpha, c0v.x);
            v.y = fmaf(acc[4 * q + 1], alpha, c0v.y);
            v.z = fmaf(acc[4 * q + 2], alpha, c0v.z);
            v.w = fmaf(acc[4 * q + 3], alpha, c0v.w);
            *reinterpret_cast<float4*>(&C[off]) = v;
        }
    }
}

// ---------------------------------------------------------------------------
// Fallback f32 GEMM (used only if workspace too small)
// ---------------------------------------------------------------------------
#define GMT 64
#define GNT 64
#define GKT 32
#define GPAD 4

template <bool UT>
__global__ __launch_bounds__(256) void gemm_u(
    const float* __restrict__ X,
    const float* __restrict__ Uq,
    const float* __restrict__ C0,
    float* __restrict__ C,
    const float* __restrict__ alpha_ptr,
    float alpha_const)
{
    __shared__ float Xs[GKT][GMT + GPAD];
    __shared__ float Us[GKT][GNT + GPAD];

    const int t = threadIdx.x;
    const int m0 = blockIdx.y * GMT;
    const int n0 = blockIdx.x * GNT;
    const int tx = t & 15;
    const int ty = t >> 4;
    const int srow = t >> 2;
    const int scol = (t & 3) * 8;

    float acc[4][4] = {};

    for (int k0 = 0; k0 < NN; k0 += GKT) {
        {
            const float4* xp = reinterpret_cast<const float4*>(
                &X[(size_t)(m0 + srow) * NN + k0 + scol]);
            float4 a = xp[0], b4 = xp[1];
            Xs[scol + 0][srow] = a.x;  Xs[scol + 1][srow] = a.y;
            Xs[scol + 2][srow] = a.z;  Xs[scol + 3][srow] = a.w;
            Xs[scol + 4][srow] = b4.x; Xs[scol + 5][srow] = b4.y;
            Xs[scol + 6][srow] = b4.z; Xs[scol + 7][srow] = b4.w;
        }
        if (UT) {
            int kk = t >> 3;
            int j0 = (t & 7) * 8;
            const float4* up = reinterpret_cast<const float4*>(
                &Uq[(size_t)(k0 + kk) * NN + n0 + j0]);
            float4 a = up[0], b4 = up[1];
            Us[kk][j0 + 0] = a.x;  Us[kk][j0 + 1] = a.y;
            Us[kk][j0 + 2] = a.z;  Us[kk][j0 + 3] = a.w;
            Us[kk][j0 + 4] = b4.x; Us[kk][j0 + 5] = b4.y;
            Us[kk][j0 + 6] = b4.z; Us[kk][j0 + 7] = b4.w;
        } else {
            const float4* up = reinterpret_cast<const float4*>(
                &Uq[(size_t)(n0 + srow) * NN + k0 + scol]);
            float4 a = up[0], b4 = up[1];
            Us[scol + 0][srow] = a.x;  Us[scol + 1][srow] = a.y;
            Us[scol + 2][srow] = a.z;  Us[scol + 3][srow] = a.w;
            Us[scol + 4][srow] = b4.x; Us[scol + 5][srow] = b4.y;
            Us[scol + 6][srow] = b4.z; Us[scol + 7][srow] = b4.w;
        }
        __syncthreads();
#pragma unroll
        for (int kk = 0; kk < GKT; ++kk) {
            float a[4], bb[4];
#pragma unroll
            for (int i = 0; i < 4; ++i) a[i] = Xs[kk][ty * 4 + i];
#pragma unroll
            for (int j = 0; j < 4; ++j) bb[j] = Us[kk][tx * 4 + j];
#pragma unroll
            for (int i = 0; i < 4; ++i)
#pragma unroll
                for (int j = 0; j < 4; ++j)
                    acc[i][j] = fmaf(a[i], bb[j], acc[i][j]);
        }
        __syncthreads();
    }

    float alpha = alpha_const;
    if (alpha_ptr) alpha *= alpha_ptr[0];

#pragma unroll
    for (int i = 0; i < 4; ++i) {
        int row = m0 + ty * 4 + i;
        size_t off = (size_t)row * NN + n0 + tx * 4;
        float4 v;
        v.x = acc[i][0] * alpha;
        v.y = acc[i][1] * alpha;
        v.z = acc[i][2] * alpha;
        v.w = acc[i][3] * alpha;
        if (C0) {
            float4 c0 = *reinterpret_cast<const float4*>(&C0[off]);
            v.x += c0.x; v.y += c0.y; v.z += c0.z; v.w += c0.w;
        }
        *reinterpret_cast<float4*>(&C[off]) = v;
    }
}

// ---------------------------------------------------------------------------
// Kernel 3: fused Euler ODE via MFMA.
//  v7 = R8 skeleton with:
//   - t-channel + b1 C-init loaded per step from tcomb (f32, L1 broadcast)
//     -> 4 MFMA/step, frees aft/bt/btn/ci registers
//   - pair-product rcp: 16 v_rcp/step instead of 32 (clamped, overflow-safe)
//  Lessons kept: trans stays trans (no poly), no VGPR cap, pk-packed VALU.
// ---------------------------------------------------------------------------
__global__ __launch_bounds__(256) void ode_kernel(
    const float* __restrict__ x0,
    float* __restrict__ xc,                    // in: cond_spec
    const float* __restrict__ tcomb,           // [10][2][2][16] f32 C-init
    const float* __restrict__ A1,
    const float* __restrict__ B1,
    const float* __restrict__ W2,
    const float* __restrict__ b2,
    unsigned short* __restrict__ xf16)         // nullable bf16 out [384][4096]
{
    const int tid  = threadIdx.x;
    const int lane = tid & 63;
    const int e31  = lane & 31;
    const int hi   = lane >> 5;
    const int wv   = tid >> 6;
    const size_t eg = (size_t)blockIdx.x * 128 + (size_t)wv * 32 + e31;

    // persistent A-frags: x-channel (c=0) and cond-channel (c=1), scaled log2e
    FragU af[2][2];
#pragma unroll
    for (int mt = 0; mt < 2; ++mt) {
        int h = mt * 32 + e31;
#pragma unroll
        for (int c = 0; c < 2; ++c) {
            const float* wp = (hi ? B1 : A1) + (size_t)(h * 3 + c) * 8;
            float4 f0 = *reinterpret_cast<const float4*>(wp);
            float4 f1 = *reinterpret_cast<const float4*>(wp + 4);
            af[mt][c].u[0] = pack2bf(f0.y * L2E, f0.x * L2E);
            af[mt][c].u[1] = pack2bf(f0.w * L2E, f0.z * L2E);
            af[mt][c].u[2] = pack2bf(f1.y * L2E, f1.x * L2E);
            af[mt][c].u[3] = pack2bf(f1.w * L2E, f1.z * L2E);
        }
    }

    // W2*ln2 packed as f32x2 pairs over reg index
    f32x2 w2p0[8], w2p1[8];
#pragma unroll
    for (int r = 0; r < 16; ++r) {
        int row = (r & 3) + 8 * (r >> 2) + 4 * hi;
        float w0 = W2[row] * LN2;
        float w1 = W2[32 + row] * LN2;
        if (r & 1) { w2p0[r >> 1].y = w0; w2p1[r >> 1].y = w1; }
        else       { w2p0[r >> 1].x = w0; w2p1[r >> 1].x = w1; }
    }

    float x   = x0[eg];
    float cnd = xc[eg];
    const float db2 = DTS * b2[0];

    // cond-channel B-fragment (step-invariant)
    FragU bc;
    {
        float s, c;
        __sincosf(cnd, &s, &c);
        float cg[8], sg[8];
        cg[0] = c; sg[0] = s;
#pragma unroll
        for (int g = 1; g < 8; ++g) {
            cg[g] = cg[g - 1] * c - sg[g - 1] * s;
            sg[g] = sg[g - 1] * c + cg[g - 1] * s;
        }
#pragma unroll
        for (int t = 0; t < 4; ++t) {
            float a0 = hi ? sg[2 * t]     : cg[2 * t];
            float a1 = hi ? sg[2 * t + 1] : cg[2 * t + 1];
            bc.u[t] = pack2bf(a1, a0);
        }
    }

    // per-lane tcomb base: [k][tile][hi][r] flat; lane reads 64B per tile
    const float* tcb = tcomb + hi * 16;

#pragma unroll 1
    for (int k = 0; k < NSTEP; ++k) {
        // issue C-init loads early (L1 broadcast), consumed after harmonics
        f32x16 ci0, ci1;
        {
            const float4* p0 = reinterpret_cast<const float4*>(tcb + k * 64);
            const float4* p1 = reinterpret_cast<const float4*>(tcb + k * 64 + 32);
#pragma unroll
            for (int q = 0; q < 4; ++q) {
                float4 v0 = p0[q], v1 = p1[q];
                ci0[4 * q + 0] = v0.x; ci0[4 * q + 1] = v0.y;
                ci0[4 * q + 2] = v0.z; ci0[4 * q + 3] = v0.w;
                ci1[4 * q + 0] = v1.x; ci1[4 * q + 1] = v1.y;
                ci1[4 * q + 2] = v1.z; ci1[4 * q + 3] = v1.w;
            }
        }

        float s, c;
        __sincosf(x, &s, &c);
        float cg[8], sg[8];
        cg[0] = c; sg[0] = s;
#pragma unroll
        for (int g = 1; g < 8; ++g) {
            cg[g] = cg[g - 1] * c - sg[g - 1] * s;
            sg[g] = sg[g - 1] * c + cg[g - 1] * s;
        }
        FragU bx;
#pragma unroll
        for (int t = 0; t < 4; ++t) {
            BF2U cv;
            float a0f = hi ? sg[2 * t]     : cg[2 * t];
            float a1f = hi ? sg[2 * t + 1] : cg[2 * t + 1];
            cv.h = __float22bfloat162_rn(make_float2(a0f, a1f));  // x=lo, y=hi
            bx.u[t] = cv.u;
        }

        f32x16 a0 = __builtin_amdgcn_mfma_f32_32x32x16_bf16(af[0][0].s, bx.s, ci0, 0, 0, 0);
        f32x16 a1v = __builtin_amdgcn_mfma_f32_32x32x16_bf16(af[1][0].s, bx.s, ci1, 0, 0, 0);
        a0  = __builtin_amdgcn_mfma_f32_32x32x16_bf16(af[0][1].s, bc.s, a0, 0, 0, 0);
        a1v = __builtin_amdgcn_mfma_f32_32x32x16_bf16(af[1][1].s, bc.s, a1v, 0, 0, 0);

        // ---- silu: clamp (pk-able) -> exp batch -> +1 (pk) -> pair rcp ----
        f32x2 e0[8], e1[8];
#pragma unroll
        for (int p = 0; p < 8; ++p) {
            e0[p].x = __builtin_amdgcn_exp2f(fminf(-a0[2 * p], 24.f));
            e0[p].y = __builtin_amdgcn_exp2f(fminf(-a0[2 * p + 1], 24.f));
        }
#pragma unroll
        for (int p = 0; p < 8; ++p) {
            e1[p].x = __builtin_amdgcn_exp2f(fminf(-a1v[2 * p], 24.f));
            e1[p].y = __builtin_amdgcn_exp2f(fminf(-a1v[2 * p + 1], 24.f));
        }
#pragma unroll
        for (int p = 0; p < 8; ++p) e0[p] = e0[p] + 1.0f;   // v_pk_add
#pragma unroll
        for (int p = 0; p < 8; ++p) e1[p] = e1[p] + 1.0f;
#pragma unroll
        for (int p = 0; p < 8; ++p) {                        // pair rcp
            float rr = __builtin_amdgcn_rcpf(e0[p].x * e0[p].y);
            float ix = e0[p].y * rr;
            float iy = e0[p].x * rr;
            e0[p].x = ix; e0[p].y = iy;
        }
#pragma unroll
        for (int p = 0; p < 8; ++p) {
            float rr = __builtin_amdgcn_rcpf(e1[p].x * e1[p].y);
            float ix = e1[p].y * rr;
            float iy = e1[p].x * rr;
            e1[p].x = ix; e1[p].y = iy;
        }

        f32x2 dA = {0.f, 0.f}, dB = {0.f, 0.f};
#pragma unroll
        for (int p = 0; p < 8; ++p) {
            f32x2 q; q.x = a0[2 * p]; q.y = a0[2 * p + 1];
            f32x2 m = q * w2p0[p];          // v_pk_mul
            if (p & 1) dB = m * e0[p] + dB; // v_pk_fma
            else       dA = m * e0[p] + dA;
        }
#pragma unroll
        for (int p = 0; p < 8; ++p) {
            f32x2 q; q.x = a1v[2 * p]; q.y = a1v[2 * p + 1];
            f32x2 m = q * w2p1[p];
            if (p & 1) dB = m * e1[p] + dB;
            else       dA = m * e1[p] + dA;
        }
        f32x2 dd = dA + dB;
        float dot = dd.x + dd.y;
        float other = __shfl_xor(dot, 32, 64);
        dot += other;
        x = fmaf(DTS, dot, x) + db2;
    }

    if (xf16) {
        if (!hi) xf16[eg] = bf16of(x);
    } else {
        if (!hi) xc[eg] = x;
    }
}

// ---------------------------------------------------------------------------
extern "C" void kernel_launch(void* const* d_in, const int* in_sizes, int n_in,
                              void* d_out, int out_size, void* d_ws, size_t ws_size,
                              hipStream_t stream) {
    const float* hd  = (const float*)d_in[0];
    const float* x0  = (const float*)d_in[1];
    const float* U   = (const float*)d_in[2];
    const float* Wk  = (const float*)d_in[3];
    const float* bk  = (const float*)d_in[4];
    const float* Wad = (const float*)d_in[5];
    const float* bad = (const float*)d_in[6];
    const float* kg  = (const float*)d_in[7];
    const float* fg  = (const float*)d_in[8];
    const float* A1  = (const float*)d_in[9];
    const float* B1  = (const float*)d_in[10];
    const float* b1  = (const float*)d_in[11];
    const float* W2  = (const float*)d_in[12];
    const float* b2  = (const float*)d_in[13];
    float* out = (float*)d_out;

    unsigned char* ws = (unsigned char*)d_ws;
    const size_t offBase = 0;                       // base f32, 6291456 B
    const size_t offXC   = 6291456;                 // xc f32,   6291456 B
    const size_t offTC   = 12582912;                // tcomb f32, 2560 B (pad 4096)
    const size_t offB16  = 12587008;                // base16, 3145728 B
    const size_t offXF   = 15732736;                // xf16,   3145728 B
    const size_t offU16  = 18878464;                // 33554432 B
    const size_t offUT   = 52432896;                // 33554432 B
    const size_t needFast = 85987328;

    float* base  = (float*)(ws + offBase);
    float* xc    = (float*)(ws + offXC);
    float* tcomb = (float*)(ws + offTC);

    const bool fast = (ws_size >= needFast);

    if (fast) {
        unsigned short* base16 = (unsigned short*)(ws + offB16);
        unsigned short* xf16   = (unsigned short*)(ws + offXF);
        unsigned short* U16    = (unsigned short*)(ws + offU16);
        unsigned short* UT16   = (unsigned short*)(ws + offUT);

        u_convert_kernel<<<dim3(64, 64), 256, 0, stream>>>(U, U16, UT16);
        base_pred_kernel<<<(BB * NN) / 256, 256, 0, stream>>>(
            hd, Wk, bk, Wad, bad, kg, base, base16);
        tcomb_kernel<<<3, 256, 0, stream>>>(A1, B1, b1, tcomb);
        // GEMM1: xc[row][m] = (1/64) * sum_k base16[row][k] * UT16[m][k]
        gemm_mfma64<false><<<dim3(NN / 64, BLN / 64), 256, 0, stream>>>(
            base16, UT16, nullptr, xc, nullptr, 1.0f / 64.0f);
        // ODE: cond -> x_final (bf16, natural layout)
        ode_kernel<<<ELEMS / 128, 256, 0, stream>>>(
            x0, xc, tcomb, A1, B1, W2, b2, xf16);
        // GEMM2: out[row][m] = base + fg*64 * sum_k U16[m][k] * xf16[row][k]
        gemm_mfma64<true><<<dim3(BLN / 64, NN / 64), 256, 0, stream>>>(
            U16, xf16, base, out, fg, 64.0f);
    } else {
        base_pred_kernel<<<(BB * NN) / 256, 256, 0, stream>>>(
            hd, Wk, bk, Wad, bad, kg, base, nullptr);
        tcomb_kernel<<<3, 256, 0, stream>>>(A1, B1, b1, tcomb);
        gemm_u<true><<<dim3(NN / GNT, BLN / GMT), 256, 0, stream>>>(
            base, U, nullptr, xc, nullptr, 1.0f / 64.0f);
        ode_kernel<<<ELEMS / 128, 256, 0, stream>>>(
            x0, xc, tcomb, A1, B1, W2, b2, nullptr);
        gemm_u<false><<<dim3(NN / GNT, BLN / GMT), 256, 0, stream>>>(
            xc, U, base, out, fg, 64.0f);
    }
}

// Round 10
// 509.225 us; speedup vs baseline: 1.0940x; 1.0940x over previous
//
#include <hip/hip_runtime.h>
#include <hip/hip_bf16.h>
#include <math.h>

// Problem dims (fixed by reference)
#define BB 32
#define LL 12
#define NN 4096
#define CIN 4
#define HID 64
#define GRID_F 8
#define NSTEP 10
#define DTS 0.1f
#define BLN (BB*LL)          // 384 rows (b*L+l)
#define ELEMS (BB*LL*NN)     // 1572864
#define K4 4096

#define L2E 1.4426950408889634f
#define LN2 0.6931471805599453f

typedef __attribute__((ext_vector_type(8))) short short8;
typedef __attribute__((ext_vector_type(16))) float f32x16;
typedef __attribute__((ext_vector_type(2))) float f32x2;

union FragU { unsigned u[4]; uint4 v; short8 s; };
union BF2U { __hip_bfloat162 h; unsigned u; };

__device__ __forceinline__ unsigned pack2bf(float a, float b) {
    // a -> high 16 bits, b -> low 16 bits (both RNE-rounded bf16)
    unsigned ua = __float_as_uint(a);
    unsigned ub = __float_as_uint(b);
    ua += 0x7FFFu + ((ua >> 16) & 1u);
    ub += 0x7FFFu + ((ub >> 16) & 1u);
    return (ua & 0xFFFF0000u) | (ub >> 16);
}

__device__ __forceinline__ unsigned short bf16of(float a) {
    unsigned ua = __float_as_uint(a);
    ua += 0x7FFFu + ((ua >> 16) & 1u);
    return (unsigned short)(ua >> 16);
}

__device__ __forceinline__ f32x16 fzero16() {
    f32x16 z;
#pragma unroll
    for (int i = 0; i < 16; ++i) z[i] = 0.f;
    return z;
}

// ---------------------------------------------------------------------------
// Kernel 1: base_pred[b,l,n] = prior + tanh(adapter)*kasa_gate  (f32 + bf16)
// ---------------------------------------------------------------------------
__global__ __launch_bounds__(256) void base_pred_kernel(
    const float* __restrict__ hd,   // [B][L][N][4]
    const float* __restrict__ Wk,   // [12][12]
    const float* __restrict__ bk,   // [12]
    const float* __restrict__ Wad,  // [12][12]
    const float* __restrict__ bad,  // [12]
    const float* __restrict__ kgp,  // scalar
    float* __restrict__ base,       // [384][4096]
    unsigned short* __restrict__ base16)  // nullable [384][4096] bf16
{
    int idx = blockIdx.x * 256 + threadIdx.x;     // 0 .. 131071  (b,n)
    int b = idx >> 12;
    int n = idx & 4095;
    const float* hb = hd + (size_t)b * (LL * NN * CIN) + (size_t)n * CIN;

    float h0[12];
    float prior = 0.f;
#pragma unroll
    for (int t = 0; t < 12; ++t) {
        float4 v = *reinterpret_cast<const float4*>(hb + (size_t)t * (NN * CIN));
        h0[t] = v.x;
        if (t == 11) prior = v.w;
    }
    float kgate = kgp[0];

    float kr[12];
#pragma unroll
    for (int l = 0; l < 12; ++l) {
        float p = bk[l];
#pragma unroll
        for (int t = 0; t < 12; ++t) p = fmaf(h0[t], Wk[l * 12 + t], p);
        kr[l] = p;
    }
#pragma unroll
    for (int o = 0; o < 12; ++o) {
        float p = bad[o];
#pragma unroll
        for (int l = 0; l < 12; ++l) p = fmaf(kr[l], Wad[o * 12 + l], p);
        float val = prior + tanhf(p) * kgate;
        size_t off = ((size_t)(b * 12 + o)) * NN + n;
        base[off] = val;
        if (base16) base16[off] = bf16of(val);
    }
}

// ---------------------------------------------------------------------------
// Kernel 2: t-feature table, bf16, MFMA-B-frag layout
// ---------------------------------------------------------------------------
__global__ void tfeat_kernel(unsigned short* __restrict__ tf16)
{
    int idx = blockIdx.x * blockDim.x + threadIdx.x;
    if (idx >= NSTEP * 16) return;
    int k = idx >> 4;
    int r = idx & 15;
    int hi = r >> 3;
    int j = r & 7;
    float ang = DTS * (float)k * (float)(j + 1);
    float v = hi ? sinf(ang) : cosf(ang);
    tf16[idx] = bf16of(v);
}

// ---------------------------------------------------------------------------
// Kernel 2b: U f32 [n][m] -> U16 bf16 [n][m]  and  UT16 bf16 [m][n]
// ---------------------------------------------------------------------------
__global__ __launch_bounds__(256) void u_convert_kernel(
    const float* __restrict__ U,
    unsigned short* __restrict__ U16,
    unsigned short* __restrict__ UT16)
{
    __shared__ unsigned short tile[64][66];
    const int t = threadIdx.x;
    const int bx = blockIdx.x;   // col tile (m)
    const int by = blockIdx.y;   // row tile (n)
    {
        int r  = t >> 2;           // 0..63
        int c0 = (t & 3) * 16;
        size_t gr = (size_t)(by * 64 + r);
        size_t gc = (size_t)(bx * 64) + c0;
        const float4* src = reinterpret_cast<const float4*>(U + gr * K4 + gc);
        unsigned ou[8];
#pragma unroll
        for (int i = 0; i < 4; ++i) {
            float4 v = src[i];
            ou[2 * i]     = pack2bf(v.y, v.x);
            ou[2 * i + 1] = pack2bf(v.w, v.z);
        }
        uint4* dst = reinterpret_cast<uint4*>(&U16[gr * K4 + gc]);
        dst[0] = make_uint4(ou[0], ou[1], ou[2], ou[3]);
        dst[1] = make_uint4(ou[4], ou[5], ou[6], ou[7]);
#pragma unroll
        for (int i = 0; i < 8; ++i) {
            tile[r][c0 + 2 * i]     = (unsigned short)(ou[i] & 0xFFFFu);
            tile[r][c0 + 2 * i + 1] = (unsigned short)(ou[i] >> 16);
        }
    }
    __syncthreads();
    {
        int c  = t >> 2;           // local col
        int r0 = (t & 3) * 16;
        unsigned ou[8];
#pragma unroll
        for (int i = 0; i < 8; ++i) {
            unsigned lo = tile[r0 + 2 * i][c];
            unsigned hi = tile[r0 + 2 * i + 1][c];
            ou[i] = lo | (hi << 16);
        }
        size_t gm = (size_t)(bx * 64 + c);
        size_t gn = (size_t)(by * 64) + r0;
        uint4* dst = reinterpret_cast<uint4*>(&UT16[gm * K4 + gn]);
        dst[0] = make_uint4(ou[0], ou[1], ou[2], ou[3]);
        dst[1] = make_uint4(ou[4], ou[5], ou[6], ou[7]);
    }
}

// ---------------------------------------------------------------------------
// MFMA GEMM (64x64 tile, 384 blocks -> fills the 256-CU chip):
//   D[M'][N'] = alpha * A·Bt^T   (both operands k-contiguous bf16)
//   TRANS_STORE=false: C[d_m][d_n] = alpha*D        (GEMM1: C=xc f32)
//   TRANS_STORE=true : C[d_n][d_m] = C0 + alpha*D   (GEMM2: C=out, C0=base)
// 4 waves (2x2) of 32x32, BK=64, double-buffered swizzled LDS.
// ---------------------------------------------------------------------------
template <bool TRANS_STORE>
__global__ __launch_bounds__(256) void gemm_mfma64(
    const unsigned short* __restrict__ A,
    const unsigned short* __restrict__ Bt,
    const float* __restrict__ C0,
    float* __restrict__ C,
    const float* __restrict__ alpha_ptr,
    float alpha_const)
{
    __shared__ uint4 lds4[2][1024];   // [buf][A 8KB | B 8KB]
    unsigned char* ldsc = reinterpret_cast<unsigned char*>(&lds4[0][0]);

    const int tid  = threadIdx.x;
    const int lane = tid & 63;
    const int l31  = lane & 31;
    const int hi   = lane >> 5;
    const int w    = tid >> 6;
    const int wr   = w >> 1;
    const int wc   = w & 1;
    const int m0   = blockIdx.y * 64;
    const int n0   = blockIdx.x * 64;

    // staging: 128 rows (A 0..63 | B 64..127), 2 threads/row, 64B each
    const int srow = tid >> 1;
    const int skb  = (tid & 1) * 64;
    const bool isB = srow >= 64;
    const int  rloc = srow & 63;
    const unsigned char* gsrc = (isB ? (const unsigned char*)Bt + ((size_t)(n0 + rloc) * K4) * 2
                                     : (const unsigned char*)A  + ((size_t)(m0 + rloc) * K4) * 2) + skb;
    const int swbase = (isB ? 8192 : 0) + rloc * 128;
    const int sswz   = (rloc & 7) << 4;

    uint4 rg[4];
    auto LOADG = [&](int kt) {
        const size_t kby = (size_t)kt * 128;
#pragma unroll
        for (int i = 0; i < 4; ++i)
            rg[i] = *reinterpret_cast<const uint4*>(gsrc + kby + i * 16);
    };
    auto WRITE_LDS = [&](int buf) {
        unsigned char* p = ldsc + buf * 16384;
#pragma unroll
        for (int i = 0; i < 4; ++i)
            *reinterpret_cast<uint4*>(p + (swbase + ((skb + i * 16) ^ sswz))) = rg[i];
    };

    f32x16 acc = fzero16();

    const int raw = wr * 32 + l31;
    const int rbw = wc * 32 + l31;
    const int khb = hi * 16;
    const int aswz = (raw & 7) << 4;
    const int bswz = (rbw & 7) << 4;

    LOADG(0);
    WRITE_LDS(0);

    for (int kt = 0; kt < K4 / 64; ++kt) {
        __syncthreads();
        if (kt + 1 < K4 / 64) LOADG(kt + 1);
        const unsigned char* p = ldsc + (kt & 1) * 16384;
#pragma unroll
        for (int ks = 0; ks < 4; ++ks) {
            const int kc = ks * 32 + khb;
            short8 a = *reinterpret_cast<const short8*>(p + (raw * 128 + (kc ^ aswz)));
            short8 b = *reinterpret_cast<const short8*>(p + 8192 + (rbw * 128 + (kc ^ bswz)));
            acc = __builtin_amdgcn_mfma_f32_32x32x16_bf16(a, b, acc, 0, 0, 0);
        }
        if (kt + 1 < K4 / 64) WRITE_LDS((kt + 1) & 1);
    }

    float alpha = alpha_const;
    if (alpha_ptr) alpha *= alpha_ptr[0];

    if (!TRANS_STORE) {
        int colg = n0 + wc * 32 + l31;
        int rowb = m0 + wr * 32 + 4 * hi;
#pragma unroll
        for (int r = 0; r < 16; ++r) {
            int row = rowb + (r & 3) + 8 * (r >> 2);
            C[(size_t)row * K4 + colg] = acc[r] * alpha;
        }
    } else {
        int rowo = n0 + wc * 32 + l31;
        int mb   = m0 + wr * 32 + 4 * hi;
#pragma unroll
        for (int q = 0; q < 4; ++q) {
            size_t off = (size_t)rowo * K4 + mb + 8 * q;
            float4 c0v = *reinterpret_cast<const float4*>(&C0[off]);
            float4 v;
            v.x = fmaf(acc[4 * q + 0], alpha, c0v.x);
            v.y = fmaf(acc[4 * q + 1], alpha, c0v.y);
            v.z = fmaf(acc[4 * q + 2], alpha, c0v.z);
            v.w = fmaf(acc[4 * q + 3], alpha, c0v.w);
            *reinterpret_cast<float4*>(&C[off]) = v;
        }
    }
}

// ---------------------------------------------------------------------------
// Fallback f32 GEMM (used only if workspace too small)
// ---------------------------------------------------------------------------
#define GMT 64
#define GNT 64
#define GKT 32
#define GPAD 4

template <bool UT>
__global__ __launch_bounds__(256) void gemm_u(
    const float* __restrict__ X,
    const float* __restrict__ Uq,
    const float* __restrict__ C0,
    float* __restrict__ C,
    const float* __restrict__ alpha_ptr,
    float alpha_const)
{
    __shared__ float Xs[GKT][GMT + GPAD];
    __shared__ float Us[GKT][GNT + GPAD];

    const int t = threadIdx.x;
    const int m0 = blockIdx.y * GMT;
    const int n0 = blockIdx.x * GNT;
    const int tx = t & 15;
    const int ty = t >> 4;
    const int srow = t >> 2;
    const int scol = (t & 3) * 8;

    float acc[4][4] = {};

    for (int k0 = 0; k0 < NN; k0 += GKT) {
        {
            const float4* xp = reinterpret_cast<const float4*>(
                &X[(size_t)(m0 + srow) * NN + k0 + scol]);
            float4 a = xp[0], b4 = xp[1];
            Xs[scol + 0][srow] = a.x;  Xs[scol + 1][srow] = a.y;
            Xs[scol + 2][srow] = a.z;  Xs[scol + 3][srow] = a.w;
            Xs[scol + 4][srow] = b4.x; Xs[scol + 5][srow] = b4.y;
            Xs[scol + 6][srow] = b4.z; Xs[scol + 7][srow] = b4.w;
        }
        if (UT) {
            int kk = t >> 3;
            int j0 = (t & 7) * 8;
            const float4* up = reinterpret_cast<const float4*>(
                &Uq[(size_t)(k0 + kk) * NN + n0 + j0]);
            float4 a = up[0], b4 = up[1];
            Us[kk][j0 + 0] = a.x;  Us[kk][j0 + 1] = a.y;
            Us[kk][j0 + 2] = a.z;  Us[kk][j0 + 3] = a.w;
            Us[kk][j0 + 4] = b4.x; Us[kk][j0 + 5] = b4.y;
            Us[kk][j0 + 6] = b4.z; Us[kk][j0 + 7] = b4.w;
        } else {
            const float4* up = reinterpret_cast<const float4*>(
                &Uq[(size_t)(n0 + srow) * NN + k0 + scol]);
            float4 a = up[0], b4 = up[1];
            Us[scol + 0][srow] = a.x;  Us[scol + 1][srow] = a.y;
            Us[scol + 2][srow] = a.z;  Us[scol + 3][srow] = a.w;
            Us[scol + 4][srow] = b4.x; Us[scol + 5][srow] = b4.y;
            Us[scol + 6][srow] = b4.z; Us[scol + 7][srow] = b4.w;
        }
        __syncthreads();
#pragma unroll
        for (int kk = 0; kk < GKT; ++kk) {
            float a[4], bb[4];
#pragma unroll
            for (int i = 0; i < 4; ++i) a[i] = Xs[kk][ty * 4 + i];
#pragma unroll
            for (int j = 0; j < 4; ++j) bb[j] = Us[kk][tx * 4 + j];
#pragma unroll
            for (int i = 0; i < 4; ++i)
#pragma unroll
                for (int j = 0; j < 4; ++j)
                    acc[i][j] = fmaf(a[i], bb[j], acc[i][j]);
        }
        __syncthreads();
    }

    float alpha = alpha_const;
    if (alpha_ptr) alpha *= alpha_ptr[0];

#pragma unroll
    for (int i = 0; i < 4; ++i) {
        int row = m0 + ty * 4 + i;
        size_t off = (size_t)row * NN + n0 + tx * 4;
        float4 v;
        v.x = acc[i][0] * alpha;
        v.y = acc[i][1] * alpha;
        v.z = acc[i][2] * alpha;
        v.w = acc[i][3] * alpha;
        if (C0) {
            float4 c0 = *reinterpret_cast<const float4*>(&C0[off]);
            v.x += c0.x; v.y += c0.y; v.z += c0.z; v.w += c0.w;
        }
        *reinterpret_cast<float4*>(&C[off]) = v;
    }
}

// ---------------------------------------------------------------------------
// Kernel 3: fused Euler ODE via MFMA.
//  v8 = R8's exact instruction mix (6 MFMA/step, plain per-h exp+rcp silu,
//  pk-packed VALU), restructured TILE-SEQUENTIALLY to cut peak live regs:
//    tile0: 3 MFMA -> silu -> partial dot;  tile1: same.
//  One f32x16 accumulator + one f32x2 e[8] reused; bt loaded at loop top
//  (no btn prefetch). Goal: unified regs <=128 -> 4 waves/SIMD -> trans/VALU
//  overlap across waves. Lessons kept: no rcp-product tricks, no VMEM C-init,
//  no VGPR cap.
// ---------------------------------------------------------------------------
__global__ __launch_bounds__(256) void ode_kernel(
    const float* __restrict__ x0,
    float* __restrict__ xc,                    // in: cond_spec
    const unsigned short* __restrict__ tf16,   // [10][16] bf16 t-features
    const float* __restrict__ A1,
    const float* __restrict__ B1,
    const float* __restrict__ b1,
    const float* __restrict__ W2,
    const float* __restrict__ b2,
    unsigned short* __restrict__ xf16)         // nullable bf16 out [384][4096]
{
    const int tid  = threadIdx.x;
    const int lane = tid & 63;
    const int e31  = lane & 31;
    const int hi   = lane >> 5;
    const int wv   = tid >> 6;
    const size_t eg = (size_t)blockIdx.x * 128 + (size_t)wv * 32 + e31;

    // persistent A-frags for all 3 channels (x=0, cond=1, t=2), scaled log2e
    FragU af[2][3];
#pragma unroll
    for (int mt = 0; mt < 2; ++mt) {
        int h = mt * 32 + e31;
#pragma unroll
        for (int c = 0; c < 3; ++c) {
            const float* wp = (hi ? B1 : A1) + (size_t)(h * 3 + c) * 8;
            float4 f0 = *reinterpret_cast<const float4*>(wp);
            float4 f1 = *reinterpret_cast<const float4*>(wp + 4);
            af[mt][c].u[0] = pack2bf(f0.y * L2E, f0.x * L2E);
            af[mt][c].u[1] = pack2bf(f0.w * L2E, f0.z * L2E);
            af[mt][c].u[2] = pack2bf(f1.y * L2E, f1.x * L2E);
            af[mt][c].u[3] = pack2bf(f1.w * L2E, f1.z * L2E);
        }
    }

    // C-init (b1*log2e) and W2*ln2 packed as f32x2 pairs over reg index
    f32x16 ci0, ci1;
    f32x2 w2p0[8], w2p1[8];
#pragma unroll
    for (int r = 0; r < 16; ++r) {
        int row = (r & 3) + 8 * (r >> 2) + 4 * hi;
        ci0[r] = b1[row] * L2E;
        ci1[r] = b1[32 + row] * L2E;
        float w0 = W2[row] * LN2;
        float w1 = W2[32 + row] * LN2;
        if (r & 1) { w2p0[r >> 1].y = w0; w2p1[r >> 1].y = w1; }
        else       { w2p0[r >> 1].x = w0; w2p1[r >> 1].x = w1; }
    }

    float x   = x0[eg];
    float cnd = xc[eg];
    const float db2 = DTS * b2[0];

    // cond-channel B-fragment (step-invariant)
    FragU bc;
    {
        float s, c;
        __sincosf(cnd, &s, &c);
        float cg[8], sg[8];
        cg[0] = c; sg[0] = s;
#pragma unroll
        for (int g = 1; g < 8; ++g) {
            cg[g] = cg[g - 1] * c - sg[g - 1] * s;
            sg[g] = sg[g - 1] * c + cg[g - 1] * s;
        }
#pragma unroll
        for (int t = 0; t < 4; ++t) {
            float a0 = hi ? sg[2 * t]     : cg[2 * t];
            float a1 = hi ? sg[2 * t + 1] : cg[2 * t + 1];
            bc.u[t] = pack2bf(a1, a0);
        }
    }

#pragma unroll 1
    for (int k = 0; k < NSTEP; ++k) {
        // t-fragment for this step (16B L1-resident broadcast; hidden by sincos)
        FragU bt;
        bt.v = *reinterpret_cast<const uint4*>(tf16 + k * 16 + hi * 8);

        float s, c;
        __sincosf(x, &s, &c);
        float cg[8], sg[8];
        cg[0] = c; sg[0] = s;
#pragma unroll
        for (int g = 1; g < 8; ++g) {
            cg[g] = cg[g - 1] * c - sg[g - 1] * s;
            sg[g] = sg[g - 1] * c + cg[g - 1] * s;
        }
        FragU bx;
#pragma unroll
        for (int t = 0; t < 4; ++t) {
            BF2U cv;
            float a0f = hi ? sg[2 * t]     : cg[2 * t];
            float a1f = hi ? sg[2 * t + 1] : cg[2 * t + 1];
            cv.h = __float22bfloat162_rn(make_float2(a0f, a1f));  // x=lo, y=hi
            bx.u[t] = cv.u;
        }

        f32x2 dA = {0.f, 0.f}, dB = {0.f, 0.f};

        // ---- tile 0: 3 MFMA -> silu -> partial dot ----
        {
            f32x16 aa = __builtin_amdgcn_mfma_f32_32x32x16_bf16(af[0][0].s, bx.s, ci0, 0, 0, 0);
            aa = __builtin_amdgcn_mfma_f32_32x32x16_bf16(af[0][1].s, bc.s, aa, 0, 0, 0);
            aa = __builtin_amdgcn_mfma_f32_32x32x16_bf16(af[0][2].s, bt.s, aa, 0, 0, 0);

            f32x2 e[8];
#pragma unroll
            for (int p = 0; p < 8; ++p) {
                e[p].x = __builtin_amdgcn_exp2f(-aa[2 * p]);
                e[p].y = __builtin_amdgcn_exp2f(-aa[2 * p + 1]);
            }
#pragma unroll
            for (int p = 0; p < 8; ++p) e[p] = e[p] + 1.0f;   // v_pk_add
#pragma unroll
            for (int p = 0; p < 8; ++p) {
                e[p].x = __builtin_amdgcn_rcpf(e[p].x);
                e[p].y = __builtin_amdgcn_rcpf(e[p].y);
            }
#pragma unroll
            for (int p = 0; p < 8; ++p) {
                f32x2 q; q.x = aa[2 * p]; q.y = aa[2 * p + 1];
                f32x2 m = q * w2p0[p];          // v_pk_mul
                if (p & 1) dB = m * e[p] + dB;  // v_pk_fma
                else       dA = m * e[p] + dA;
            }
        }

        // ---- tile 1: 3 MFMA -> silu -> partial dot ----
        {
            f32x16 aa = __builtin_amdgcn_mfma_f32_32x32x16_bf16(af[1][0].s, bx.s, ci1, 0, 0, 0);
            aa = __builtin_amdgcn_mfma_f32_32x32x16_bf16(af[1][1].s, bc.s, aa, 0, 0, 0);
            aa = __builtin_amdgcn_mfma_f32_32x32x16_bf16(af[1][2].s, bt.s, aa, 0, 0, 0);

            f32x2 e[8];
#pragma unroll
            for (int p = 0; p < 8; ++p) {
                e[p].x = __builtin_amdgcn_exp2f(-aa[2 * p]);
                e[p].y = __builtin_amdgcn_exp2f(-aa[2 * p + 1]);
            }
#pragma unroll
            for (int p = 0; p < 8; ++p) e[p] = e[p] + 1.0f;
#pragma unroll
            for (int p = 0; p < 8; ++p) {
                e[p].x = __builtin_amdgcn_rcpf(e[p].x);
                e[p].y = __builtin_amdgcn_rcpf(e[p].y);
            }
#pragma unroll
            for (int p = 0; p < 8; ++p) {
                f32x2 q; q.x = aa[2 * p]; q.y = aa[2 * p + 1];
                f32x2 m = q * w2p1[p];
                if (p & 1) dB = m * e[p] + dB;
                else       dA = m * e[p] + dA;
            }
        }

        f32x2 dd = dA + dB;
        float dot = dd.x + dd.y;
        float other = __shfl_xor(dot, 32, 64);
        dot += other;
        x = fmaf(DTS, dot, x) + db2;
    }

    if (xf16) {
        if (!hi) xf16[eg] = bf16of(x);
    } else {
        if (!hi) xc[eg] = x;
    }
}

// ---------------------------------------------------------------------------
extern "C" void kernel_launch(void* const* d_in, const int* in_sizes, int n_in,
                              void* d_out, int out_size, void* d_ws, size_t ws_size,
                              hipStream_t stream) {
    const float* hd  = (const float*)d_in[0];
    const float* x0  = (const float*)d_in[1];
    const float* U   = (const float*)d_in[2];
    const float* Wk  = (const float*)d_in[3];
    const float* bk  = (const float*)d_in[4];
    const float* Wad = (const float*)d_in[5];
    const float* bad = (const float*)d_in[6];
    const float* kg  = (const float*)d_in[7];
    const float* fg  = (const float*)d_in[8];
    const float* A1  = (const float*)d_in[9];
    const float* B1  = (const float*)d_in[10];
    const float* b1  = (const float*)d_in[11];
    const float* W2  = (const float*)d_in[12];
    const float* b2  = (const float*)d_in[13];
    float* out = (float*)d_out;

    unsigned char* ws = (unsigned char*)d_ws;
    const size_t offBase = 0;                       // base f32, 6291456 B
    const size_t offXC   = 6291456;                 // xc f32,   6291456 B
    const size_t offTF   = 12582912;                // tf16, 320 B (pad 1024)
    const size_t offB16  = 12583936;                // base16, 3145728 B
    const size_t offXF   = 15729664;                // xf16,   3145728 B
    const size_t offU16  = 18875392;                // 33554432 B
    const size_t offUT   = 52429824;                // 33554432 B
    const size_t needFast = 85984256;

    float* base = (float*)(ws + offBase);
    float* xc   = (float*)(ws + offXC);
    unsigned short* tf16 = (unsigned short*)(ws + offTF);

    const bool fast = (ws_size >= needFast);

    if (fast) {
        unsigned short* base16 = (unsigned short*)(ws + offB16);
        unsigned short* xf16   = (unsigned short*)(ws + offXF);
        unsigned short* U16    = (unsigned short*)(ws + offU16);
        unsigned short* UT16   = (unsigned short*)(ws + offUT);

        u_convert_kernel<<<dim3(64, 64), 256, 0, stream>>>(U, U16, UT16);
        base_pred_kernel<<<(BB * NN) / 256, 256, 0, stream>>>(
            hd, Wk, bk, Wad, bad, kg, base, base16);
        tfeat_kernel<<<1, 256, 0, stream>>>(tf16);
        // GEMM1: xc[row][m] = (1/64) * sum_k base16[row][k] * UT16[m][k]
        gemm_mfma64<false><<<dim3(NN / 64, BLN / 64), 256, 0, stream>>>(
            base16, UT16, nullptr, xc, nullptr, 1.0f / 64.0f);
        // ODE: cond -> x_final (bf16, natural layout)
        ode_kernel<<<ELEMS / 128, 256, 0, stream>>>(
            x0, xc, tf16, A1, B1, b1, W2, b2, xf16);
        // GEMM2: out[row][m] = base + fg*64 * sum_k U16[m][k] * xf16[row][k]
        gemm_mfma64<true><<<dim3(BLN / 64, NN / 64), 256, 0, stream>>>(
            U16, xf16, base, out, fg, 64.0f);
    } else {
        base_pred_kernel<<<(BB * NN) / 256, 256, 0, stream>>>(
            hd, Wk, bk, Wad, bad, kg, base, nullptr);
        tfeat_kernel<<<1, 256, 0, stream>>>(tf16);
        gemm_u<true><<<dim3(NN / GNT, BLN / GMT), 256, 0, stream>>>(
            base, U, nullptr, xc, nullptr, 1.0f / 64.0f);
        ode_kernel<<<ELEMS / 128, 256, 0, stream>>>(
            x0, xc, tf16, A1, B1, b1, W2, b2, nullptr);
        gemm_u<false><<<dim3(NN / GNT, BLN / GMT), 256, 0, stream>>>(
            xc, U, base, out, fg, 64.0f);
    }
}